// Round 16
// baseline (422.259 us; speedup 1.0000x reference)
//
#include <hip/hip_runtime.h>
#include <hip/hip_bf16.h>
#include <math.h>

#define LR_SLOPE 0.2f

typedef __attribute__((ext_vector_type(8))) short bf16x8;
typedef __attribute__((ext_vector_type(4))) float f32x4;
typedef __attribute__((ext_vector_type(2))) float f32x2;

// fp32 -> bf16 round-to-nearest-even (bit trick)
__device__ __forceinline__ unsigned short f2bf(float f) {
    unsigned u = __float_as_uint(f);
    u = (u + 0x7FFFu + ((u >> 16) & 1u)) >> 16;
    return (unsigned short)u;
}

// 2 packed bf16 (one u32) -> f32x2
__device__ __forceinline__ f32x2 bf2f2(unsigned u) {
    f32x2 r;
    r.x = __uint_as_float(u << 16);
    r.y = __uint_as_float(u & 0xffff0000u);
    return r;
}

// packed 2xfp32 helpers -> v_pk_fma_f32 / v_pk_max_f32 on CDNA
__device__ __forceinline__ f32x2 pk_fma(f32x2 a, f32x2 b, f32x2 c) {
    return __builtin_elementwise_fma(a, b, c);
}
__device__ __forceinline__ f32x2 pk_max(f32x2 a, f32x2 b) {
    return __builtin_elementwise_max(a, b);
}

// v_add_f32 with DPP row-rotate: p += rotate_within_16(p, CTRL). Pure VALU.
template <int CTRL>
__device__ __forceinline__ float add_dpp(float v) {
    const int r = __builtin_amdgcn_update_dpp(0, __float_as_int(v),
                                              CTRL, 0xF, 0xF, true);
    return v + __int_as_float(r);
}

// ---------- small GEMM (MLP, N=64): out = act(A@W + bias), fp32 or bf16 out ----------
__global__ __launch_bounds__(256) void gemm_bias_act(
    const float* __restrict__ A, const float* __restrict__ W,
    const float* __restrict__ bias, float* __restrict__ outf,
    short* __restrict__ outb, int M, int N, int K, int do_relu)
{
    __shared__ float As[16][64];
    __shared__ float Ws[16][64];
    const int tid = threadIdx.x;
    const int tx = tid & 15;
    const int ty = tid >> 4;
    const int row0 = blockIdx.x * 64;
    const int col0 = blockIdx.y * 64;

    float acc[4][4] = {{0.f}};

    for (int kk = 0; kk < K; kk += 16) {
        {
            const int ra = tid >> 2;
            const int ka = (tid & 3) << 2;
            float4 v = make_float4(0.f, 0.f, 0.f, 0.f);
            const int r = row0 + ra;
            if (r < M)
                v = *reinterpret_cast<const float4*>(&A[(size_t)r * K + kk + ka]);
            As[ka + 0][ra] = v.x;
            As[ka + 1][ra] = v.y;
            As[ka + 2][ra] = v.z;
            As[ka + 3][ra] = v.w;
        }
        {
            const int rw = tid >> 4;
            const int cw = (tid & 15) << 2;
            float4 v = *reinterpret_cast<const float4*>(
                &W[(size_t)(kk + rw) * N + col0 + cw]);
            *reinterpret_cast<float4*>(&Ws[rw][cw]) = v;
        }
        __syncthreads();
#pragma unroll
        for (int k = 0; k < 16; ++k) {
            const float4 a = *reinterpret_cast<const float4*>(&As[k][ty * 4]);
            const float4 b = *reinterpret_cast<const float4*>(&Ws[k][tx * 4]);
            const float av[4] = {a.x, a.y, a.z, a.w};
            const float bv[4] = {b.x, b.y, b.z, b.w};
#pragma unroll
            for (int i = 0; i < 4; ++i)
#pragma unroll
                for (int j = 0; j < 4; ++j)
                    acc[i][j] += av[i] * bv[j];
        }
        __syncthreads();
    }

    const int cbase = col0 + tx * 4;
#pragma unroll
    for (int i = 0; i < 4; ++i) {
        const int r = row0 + ty * 4 + i;
        if (r >= M) continue;
        float v[4];
#pragma unroll
        for (int j = 0; j < 4; ++j) {
            v[j] = acc[i][j] + bias[cbase + j];
            if (do_relu) v[j] = fmaxf(v[j], 0.f);
        }
        if (outb) {
            short4 s;
            s.x = (short)f2bf(v[0]); s.y = (short)f2bf(v[1]);
            s.z = (short)f2bf(v[2]); s.w = (short)f2bf(v[3]);
            *reinterpret_cast<short4*>(&outb[(size_t)r * N + cbase]) = s;
        } else {
            float4 o; o.x = v[0]; o.y = v[1]; o.z = v[2]; o.w = v[3];
            *reinterpret_cast<float4*>(&outf[(size_t)r * N + cbase]) = o;
        }
    }
}

// ---------- all 4 weight transposes + bf16 convert in one launch ----------
__global__ void wtrans_all_k(
    const float* __restrict__ Wl1, const float* __restrict__ Wr1,
    const float* __restrict__ Wl2, const float* __restrict__ Wr2,
    short* __restrict__ o1, short* __restrict__ o2,
    short* __restrict__ o3, short* __restrict__ o4)
{
    const int i = blockIdx.x * 256 + threadIdx.x;
    const int S1 = 256 * 64, S2 = 256 * 256;
    if (i < S1) {
        const int n = i / 64, k = i % 64;
        o1[i] = (short)f2bf(Wl1[(size_t)k * 256 + n]);
    } else if (i < 2 * S1) {
        const int j = i - S1;
        const int n = j / 64, k = j % 64;
        o2[j] = (short)f2bf(Wr1[(size_t)k * 256 + n]);
    } else if (i < 2 * S1 + S2) {
        const int j = i - 2 * S1;
        const int n = j / 256, k = j % 256;
        o3[j] = (short)f2bf(Wl2[(size_t)k * 256 + n]);
    } else if (i < 2 * S1 + 2 * S2) {
        const int j = i - 2 * S1 - S2;
        const int n = j / 256, k = j % 256;
        o4[j] = (short)f2bf(Wr2[(size_t)k * 256 + n]);
    }
}

// ---------- MFMA dual GEMM: {out0,out1} = bf16(A @ {W0,W1} + {b0,b1}) ----------
__global__ __launch_bounds__(256) void gemm_mfma_dual(
    const short* __restrict__ A,
    const short* __restrict__ Wt0, const float* __restrict__ b0,
    short* __restrict__ out0,
    const short* __restrict__ Wt1, const float* __restrict__ b1,
    short* __restrict__ out1,
    int M, int N, int K)
{
    const short* __restrict__ Wt   = blockIdx.z ? Wt1 : Wt0;
    const float* __restrict__ bias = blockIdx.z ? b1 : b0;
    short* __restrict__ out        = blockIdx.z ? out1 : out0;

    __shared__ __align__(16) short As[4][128][8];
    __shared__ __align__(16) short Bs[4][128][8];

    const int tid = threadIdx.x;
    const int lane = tid & 63;
    const int wid = tid >> 6;
    const int wm = wid >> 1, wn = wid & 1;
    const int row0 = blockIdx.x * 128;
    const int col0 = blockIdx.y * 128;

    f32x4 acc[4][4] = {};

    const int srow = tid & 127;
    const int skg2 = tid >> 7;

    for (int kk = 0; kk < K; kk += 32) {
        {
            const int r = row0 + srow;
            bf16x8 a0 = {0, 0, 0, 0, 0, 0, 0, 0};
            bf16x8 a1 = {0, 0, 0, 0, 0, 0, 0, 0};
            if (r < M) {
                const bf16x8* p = reinterpret_cast<const bf16x8*>(
                    &A[(size_t)r * K + kk + skg2 * 16]);
                a0 = p[0]; a1 = p[1];
            }
            *reinterpret_cast<bf16x8*>(&As[skg2 * 2 + 0][srow][0]) = a0;
            *reinterpret_cast<bf16x8*>(&As[skg2 * 2 + 1][srow][0]) = a1;
        }
        {
            const float4* p = reinterpret_cast<const float4*>(
                &Wt[(size_t)(col0 + srow) * K + kk + skg2 * 16]);
            *reinterpret_cast<float4*>(&Bs[skg2 * 2 + 0][srow][0]) = p[0];
            *reinterpret_cast<float4*>(&Bs[skg2 * 2 + 1][srow][0]) = p[1];
        }
        __syncthreads();

        const int kg = lane >> 4, li = lane & 15;
        bf16x8 af[4], bfr[4];
#pragma unroll
        for (int mi = 0; mi < 4; ++mi)
            af[mi] = *reinterpret_cast<bf16x8*>(&As[kg][wm * 64 + mi * 16 + li][0]);
#pragma unroll
        for (int ni = 0; ni < 4; ++ni)
            bfr[ni] = *reinterpret_cast<bf16x8*>(&Bs[kg][wn * 64 + ni * 16 + li][0]);
#pragma unroll
        for (int mi = 0; mi < 4; ++mi)
#pragma unroll
            for (int ni = 0; ni < 4; ++ni)
                acc[mi][ni] = __builtin_amdgcn_mfma_f32_16x16x32_bf16(
                    af[mi], bfr[ni], acc[mi][ni], 0, 0, 0);
        __syncthreads();
    }

    const int li = lane & 15, lq = lane >> 4;
#pragma unroll
    for (int ni = 0; ni < 4; ++ni) {
        const int c = col0 + wn * 64 + ni * 16 + li;
        const float bv = bias[c];
#pragma unroll
        for (int mi = 0; mi < 4; ++mi) {
#pragma unroll
            for (int r = 0; r < 4; ++r) {
                const int row = row0 + wm * 64 + mi * 16 + lq * 4 + r;
                if (row < M)
                    out[(size_t)row * N + c] = (short)f2bf(acc[mi][ni][r] + bv);
            }
        }
    }
}

// ---------- CSR build ----------
__global__ void hist_k(const int* __restrict__ dst, int* __restrict__ deg, int E)
{
    const int e = blockIdx.x * blockDim.x + threadIdx.x;
    if (e < E) atomicAdd(&deg[dst[e]], 1);
}

__global__ void scan1_k(const int* __restrict__ deg, int* __restrict__ rowptr,
                        int* __restrict__ bsum, int N)
{
    __shared__ int buf[256];
    const int i = blockIdx.x * 256 + threadIdx.x;
    const int v = (i < N) ? deg[i] : 0;
    buf[threadIdx.x] = v;
    __syncthreads();
#pragma unroll
    for (int off = 1; off < 256; off <<= 1) {
        const int t = (threadIdx.x >= (unsigned)off) ? buf[threadIdx.x - off] : 0;
        __syncthreads();
        buf[threadIdx.x] += t;
        __syncthreads();
    }
    if (i < N) rowptr[i] = buf[threadIdx.x] - v;
    if (threadIdx.x == 255) bsum[blockIdx.x] = buf[255];
}

__global__ void scan2_k(int* __restrict__ bsum, int nb)
{
    __shared__ int buf[256];
    const int v = (threadIdx.x < (unsigned)nb) ? bsum[threadIdx.x] : 0;
    buf[threadIdx.x] = v;
    __syncthreads();
#pragma unroll
    for (int off = 1; off < 256; off <<= 1) {
        const int t = (threadIdx.x >= (unsigned)off) ? buf[threadIdx.x - off] : 0;
        __syncthreads();
        buf[threadIdx.x] += t;
        __syncthreads();
    }
    if (threadIdx.x < (unsigned)nb) bsum[threadIdx.x] = buf[threadIdx.x] - v;
}

__global__ void scan3_k(int* __restrict__ rowptr, const int* __restrict__ bsum,
                        int* __restrict__ cursor, int N, int E)
{
    const int i = blockIdx.x * 256 + threadIdx.x;
    if (i < N) {
        const int r = rowptr[i] + bsum[blockIdx.x];
        rowptr[i] = r;
        cursor[i] = r;
    }
    if (i == 0) rowptr[N] = E;
}

// scatter src AND the eattr payload into dst-sorted order
__global__ void scatter_k(const int* __restrict__ src, const int* __restrict__ dst,
                          const float4* __restrict__ eattr,
                          int* __restrict__ cursor,
                          int* __restrict__ ssrc, float4* __restrict__ ea_s, int E)
{
    const int e = blockIdx.x * blockDim.x + threadIdx.x;
    if (e >= E) return;
    const int d = dst[e];
    const int p = atomicAdd(&cursor[d], 1);
    ssrc[p] = src[e];
    const float4 e0 = eattr[2 * e];
    const float4 e1 = eattr[2 * e + 1];
    ea_s[2 * p] = e0;
    ea_s[2 * p + 1] = e1;
}

// ---------- fused node-centric GATv2 (scalar-uniform edge loads + DPP reduce) ----------
// TWO INDEPENDENT WAVES per 128-thread block (no __syncthreads): r13's 1-wave
// blocks capped at ~16 workgroups/CU (occ ~35%); 2 waves/block doubles resident
// waves if block-slot-limited, with only mild 2-way retire imbalance.
// Body identical to r13 (52 VGPR, no spills; r11/r12/r15 ERRATA: in-wave
// pipelining and wave/EU=8 all regress — scheduler TLP is the only lever).
template <int H, int NPW, int OB>
__global__ __launch_bounds__(128, 4) void node_gat_k(
    const short* __restrict__ xl, const short* __restrict__ xr,
    const float4* __restrict__ ea_s, const int* __restrict__ ssrc,
    const float* __restrict__ We, const float* __restrict__ att,
    const float* __restrict__ bias,
    const int* __restrict__ rowptr, void* __restrict__ outv, int N)
{
    const int lane = threadIdx.x & 63;
    const int nbase = (blockIdx.x * 2 + (threadIdx.x >> 6)) * NPW;
    if (nbase >= N) return;

    const int hc0 = (H == 4) ? (((lane >> 4) << 6) + ((lane & 15) << 2))
                             : (lane << 2);

    f32x2 we2[8][2];
#pragma unroll
    for (int t = 0; t < 8; ++t) {
        const float4 v = *reinterpret_cast<const float4*>(&We[t * 256 + hc0]);
        we2[t][0] = (f32x2){v.x, v.y};
        we2[t][1] = (f32x2){v.z, v.w};
    }
    const float4 a4 = *reinterpret_cast<const float4*>(&att[hc0]);
    const f32x2 av2[2] = {(f32x2){a4.x, a4.y}, (f32x2){a4.z, a4.w}};
    const float4 b4 = *reinterpret_cast<const float4*>(&bias[hc0]);
    const f32x2 bv2[2] = {(f32x2){b4.x, b4.y}, (f32x2){b4.z, b4.w}};

    for (int ni = 0; ni < NPW; ++ni) {
        const int n = nbase + ni;
        if (n >= N) return;
        const uint2 rp = *reinterpret_cast<const uint2*>(
            &xr[(unsigned)((n << 8) + hc0)]);
        const f32x2 xrv2[2] = {bf2f2(rp.x), bf2f2(rp.y)};

        f32x2 acc2[2] = {(f32x2){0.f, 0.f}, (f32x2){0.f, 0.f}};
        float m = -INFINITY, den = 0.f;

        // wave-uniform loop bounds -> scalar loop, scalar edge loads
        const int k0 = __builtin_amdgcn_readfirstlane(rowptr[n]);
        const int k1 = __builtin_amdgcn_readfirstlane(rowptr[n + 1]);

        auto load_e = [&](const int ks, f32x2 (&xv)[2], float (&ea)[8]) {
            const int sv = ssrc[ks];                       // uniform -> s_load
            const short* xp = xl + ((unsigned)sv << 8);    // uniform base
            const uint2 xpv = *reinterpret_cast<const uint2*>(xp + hc0);
            xv[0] = bf2f2(xpv.x);
            xv[1] = bf2f2(xpv.y);
            const float4 e0 = ea_s[2 * ks];                // uniform -> s_load
            const float4 e1 = ea_s[2 * ks + 1];
            ea[0] = e0.x; ea[1] = e0.y; ea[2] = e0.z; ea[3] = e0.w;
            ea[4] = e1.x; ea[5] = e1.y; ea[6] = e1.z; ea[7] = e1.w;
        };
        auto sc_of = [&](const f32x2 (&xv)[2], const float (&ea)[8]) -> float {
            f32x2 p2 = {0.f, 0.f};
#pragma unroll
            for (int q = 0; q < 2; ++q) {
                f32x2 s = xv[q] + xrv2[q];
#pragma unroll
                for (int t = 0; t < 8; ++t)
                    s = pk_fma((f32x2){ea[t], ea[t]}, we2[t][q], s);
                s = pk_max(s, s * LR_SLOPE);       // packed leaky relu
                p2 = pk_fma(s, av2[q], p2);
            }
            float p = p2.x + p2.y;
            // 16-lane rotation reduce on the VALU (no LDS round-trips)
            p = add_dpp<0x121>(p);   // row_ror:1
            p = add_dpp<0x122>(p);   // row_ror:2
            p = add_dpp<0x124>(p);   // row_ror:4
            p = add_dpp<0x128>(p);   // row_ror:8
            if (H == 1) {
                p += __int_as_float(__builtin_amdgcn_ds_swizzle(
                         __float_as_int(p), 0x401F));      // xor 16
                p += __shfl_xor(p, 32, 64);                // xor 32
            }
            return p;
        };

        int k = k0;
        for (; k + 4 <= k1; k += 4) {
            f32x2 x0[2], x1[2], x2[2], x3[2];
            float ea0[8], ea1[8], ea2[8], ea3[8];
            load_e(k, x0, ea0);     load_e(k + 1, x1, ea1);
            load_e(k + 2, x2, ea2); load_e(k + 3, x3, ea3);
            const float s0 = sc_of(x0, ea0);
            const float s1 = sc_of(x1, ea1);
            const float s2 = sc_of(x2, ea2);
            const float s3 = sc_of(x3, ea3);
            const float nm = fmaxf(fmaxf(m, fmaxf(s0, s1)), fmaxf(s2, s3));
            const float sc = __expf(m - nm);
            const float w0 = __expf(s0 - nm), w1 = __expf(s1 - nm);
            const float w2 = __expf(s2 - nm), w3 = __expf(s3 - nm);
            den = fmaf(den, sc, (w0 + w1) + (w2 + w3));
            const f32x2 scv = {sc, sc};
            const f32x2 w0v = {w0, w0}, w1v = {w1, w1};
            const f32x2 w2v = {w2, w2}, w3v = {w3, w3};
#pragma unroll
            for (int q = 0; q < 2; ++q)
                acc2[q] = pk_fma(acc2[q], scv,
                          pk_fma(w0v, x0[q],
                          pk_fma(w1v, x1[q],
                          pk_fma(w2v, x2[q], w3v * x3[q]))));
            m = nm;
        }
        for (; k < k1; ++k) {
            f32x2 x0[2]; float ea0[8];
            load_e(k, x0, ea0);
            const float s0 = sc_of(x0, ea0);
            const float nm = fmaxf(m, s0);
            const float sc = __expf(m - nm);
            const float w0 = __expf(s0 - nm);
            den = fmaf(den, sc, w0);
            const f32x2 scv = {sc, sc};
            const f32x2 w0v = {w0, w0};
#pragma unroll
            for (int q = 0; q < 2; ++q)
                acc2[q] = pk_fma(acc2[q], scv, w0v * x0[q]);
            m = nm;
        }

        const float inv = (den > 0.f) ? 1.f / den : 0.f;
        const f32x2 invv = {inv, inv};
        const f32x2 z2 = {0.f, 0.f};
        const f32x2 o0 = pk_max(pk_fma(acc2[0], invv, bv2[0]), z2);
        const f32x2 o1 = pk_max(pk_fma(acc2[1], invv, bv2[1]), z2);
        if (OB) {
            short4 s;
            s.x = (short)f2bf(o0.x); s.y = (short)f2bf(o0.y);
            s.z = (short)f2bf(o1.x); s.w = (short)f2bf(o1.y);
            *reinterpret_cast<short4*>(
                &((short*)outv)[(unsigned)((n << 8) + hc0)]) = s;
        } else {
            float4 o; o.x = o0.x; o.y = o0.y; o.z = o1.x; o.w = o1.y;
            *reinterpret_cast<float4*>(
                &((float*)outv)[(unsigned)((n << 8) + hc0)]) = o;
        }
    }
}

extern "C" void kernel_launch(void* const* d_in, const int* in_sizes, int n_in,
                              void* d_out, int out_size, void* d_ws, size_t ws_size,
                              hipStream_t stream)
{
    const float* x     = (const float*)d_in[0];
    const int*   eidx  = (const int*)d_in[1];
    const float* eattr = (const float*)d_in[2];
    const float* W1  = (const float*)d_in[3];
    const float* b1  = (const float*)d_in[4];
    const float* W2  = (const float*)d_in[5];
    const float* b2  = (const float*)d_in[6];
    const float* Wl1 = (const float*)d_in[7];
    const float* bl1 = (const float*)d_in[8];
    const float* Wr1 = (const float*)d_in[9];
    const float* br1 = (const float*)d_in[10];
    const float* We1 = (const float*)d_in[11];
    const float* att1 = (const float*)d_in[12];
    const float* bias1 = (const float*)d_in[13];
    const float* Wl2 = (const float*)d_in[14];
    const float* bl2 = (const float*)d_in[15];
    const float* Wr2 = (const float*)d_in[16];
    const float* br2 = (const float*)d_in[17];
    const float* We2 = (const float*)d_in[18];
    const float* att2 = (const float*)d_in[19];
    const float* bias2 = (const float*)d_in[20];

    const int N = in_sizes[0] / 32;        // 50000
    const int E = in_sizes[2] / 8;         // 800000
    const int* src = eidx;
    const int* dst = eidx + E;

    // ---- workspace layout (ea_s aliases h1+h2: both dead before CSR build) ----
    auto align256 = [](size_t v) { return (v + 255) & ~(size_t)255; };
    char* ws = (char*)d_ws;
    size_t off = 0;
    float* h1 = (float*)(ws + off);    off += align256((size_t)N * 64 * 4);
    short* h2b = (short*)(ws + off);   off += align256((size_t)N * 64 * 4);
    float4* ea_s = (float4*)h1;        // E*32B == N*128*4B exactly (25.6 MB)
    short* xl = (short*)(ws + off);    off += align256((size_t)N * 256 * 2);
    short* xr = (short*)(ws + off);    off += align256((size_t)N * 256 * 2);
    short* out1b = (short*)(ws + off); off += align256((size_t)N * 256 * 2);
    int* deg = (int*)(ws + off);       off += align256((size_t)N * 4);
    int* rowptr = (int*)(ws + off);    off += align256((size_t)(N + 1) * 4);
    int* cursor = (int*)(ws + off);    off += align256((size_t)N * 4);
    int* bsum = (int*)(ws + off);      off += align256((size_t)1024 * 4);
    int* ssrc = (int*)(ws + off);      off += align256((size_t)E * 4);
    short* wtl1 = (short*)(ws + off);  off += align256((size_t)256 * 64 * 2);
    short* wtr1 = (short*)(ws + off);  off += align256((size_t)256 * 64 * 2);
    short* wtl2 = (short*)(ws + off);  off += align256((size_t)256 * 256 * 2);
    short* wtr2 = (short*)(ws + off);  off += align256((size_t)256 * 256 * 2);
    (void)ws_size;

    float* outf = (float*)d_out;

    const int egrid1 = (E + 255) / 256;
    const int nblk = (N + 255) / 256;
    const int NPW = 4;
    const int ngat = (N + 2 * NPW - 1) / (2 * NPW);   // 2 waves (128 thr) / block

    // ---- weight transposes (bf16), one launch ----
    wtrans_all_k<<<(2 * 256 * 64 + 2 * 256 * 256 + 255) / 256, 256, 0, stream>>>(
        Wl1, Wr1, Wl2, Wr2, wtl1, wtr1, wtl2, wtr2);

    // ---- MLP encoder (h2 written as bf16 for the MFMA consumer) ----
    {
        dim3 g1((N + 63) / 64, 1);
        gemm_bias_act<<<g1, 256, 0, stream>>>(x,  W1, b1, h1, nullptr, N, 64, 32, 1);
        gemm_bias_act<<<g1, 256, 0, stream>>>(h1, W2, b2, nullptr, h2b, N, 64, 64, 1);
    }

    // ---- GAT layer 1 transforms (bf16 MFMA): h2b -> xl, xr (bf16) ----
    {
        dim3 g((N + 127) / 128, 2, 2);
        gemm_mfma_dual<<<g, 256, 0, stream>>>(h2b, wtl1, bl1, xl, wtr1, br1, xr,
                                              N, 256, 64);
    }

    // ---- CSR build (h1/h2 now dead; ea_s reuses their space) ----
    hipMemsetAsync(deg, 0, (size_t)N * 4, stream);
    hist_k<<<egrid1, 256, 0, stream>>>(dst, deg, E);
    scan1_k<<<nblk, 256, 0, stream>>>(deg, rowptr, bsum, N);
    scan2_k<<<1, 256, 0, stream>>>(bsum, nblk);
    scan3_k<<<nblk, 256, 0, stream>>>(rowptr, bsum, cursor, N, E);
    scatter_k<<<egrid1, 256, 0, stream>>>(src, dst, (const float4*)eattr,
                                          cursor, ssrc, ea_s, E);

    // ---- GAT layer 1 fused edge/softmax/agg (bf16 out) ----
    node_gat_k<4, NPW, 1><<<ngat, 128, 0, stream>>>(xl, xr, ea_s, ssrc,
                                                    We1, att1, bias1,
                                                    rowptr, out1b, N);

    // ---- GAT layer 2 transforms (bf16 MFMA): out1b -> xl, xr (bf16) ----
    {
        dim3 g((N + 127) / 128, 2, 2);
        gemm_mfma_dual<<<g, 256, 0, stream>>>(out1b, wtl2, bl2, xl, wtr2, br2, xr,
                                              N, 256, 256);
    }

    // ---- GAT layer 2 fused edge/softmax/agg (fp32 out) ----
    node_gat_k<1, NPW, 0><<<ngat, 128, 0, stream>>>(xl, xr, ea_s, ssrc,
                                                    We2, att2, bias2,
                                                    rowptr, outf, N);
}

// Round 17
// 417.892 us; speedup vs baseline: 1.0105x; 1.0105x over previous
//
#include <hip/hip_runtime.h>
#include <hip/hip_bf16.h>
#include <math.h>

#define LR_SLOPE 0.2f

typedef __attribute__((ext_vector_type(8))) short bf16x8;
typedef __attribute__((ext_vector_type(4))) float f32x4;
typedef __attribute__((ext_vector_type(2))) float f32x2;

// fp32 -> bf16 round-to-nearest-even (bit trick)
__device__ __forceinline__ unsigned short f2bf(float f) {
    unsigned u = __float_as_uint(f);
    u = (u + 0x7FFFu + ((u >> 16) & 1u)) >> 16;
    return (unsigned short)u;
}

// 2 packed bf16 (one u32) -> f32x2
__device__ __forceinline__ f32x2 bf2f2(unsigned u) {
    f32x2 r;
    r.x = __uint_as_float(u << 16);
    r.y = __uint_as_float(u & 0xffff0000u);
    return r;
}

// packed 2xfp32 helpers -> v_pk_fma_f32 / v_pk_max_f32 on CDNA
__device__ __forceinline__ f32x2 pk_fma(f32x2 a, f32x2 b, f32x2 c) {
    return __builtin_elementwise_fma(a, b, c);
}
__device__ __forceinline__ f32x2 pk_max(f32x2 a, f32x2 b) {
    return __builtin_elementwise_max(a, b);
}

// v_add_f32 with DPP row-rotate: p += rotate_within_16(p, CTRL). Pure VALU.
template <int CTRL>
__device__ __forceinline__ float add_dpp(float v) {
    const int r = __builtin_amdgcn_update_dpp(0, __float_as_int(v),
                                              CTRL, 0xF, 0xF, true);
    return v + __int_as_float(r);
}

// ---------- fused MLP encoder: h2 = relu(relu(x@W1+b1)@W2+b2), bf16 out ----------
// 64-row tile per block, 256 threads, 4x4 micro. h1 never leaves LDS.
// (verified passing in r11/r12 builds)
__global__ __launch_bounds__(256) void fused_mlp_k(
    const float* __restrict__ x,    // [M][32]
    const float* __restrict__ W1,   // [32][64]
    const float* __restrict__ b1,
    const float* __restrict__ W2,   // [64][64]
    const float* __restrict__ b2,
    short* __restrict__ h2b,        // [M][64] bf16
    int M)
{
    __shared__ float smem[4096 + 64 * 68];
    float* As  = smem;          // [32][64]  stage-1 A, [k][m]
    float* Ws  = smem + 2048;   // [32][64]  stage-1 W, [k][n]
    float* Hs  = smem + 4096;   // [64][68]  h1, [k][m], pad 68
    float* Ws2 = smem;          // [64][64]  stage-2 W (aliases As+Ws)

    const int tid = threadIdx.x;
    const int tx = tid & 15;
    const int ty = tid >> 4;
    const int row0 = blockIdx.x * 64;

    // stage x tile -> As[k][m]
    {
        const int r = tid >> 2;
        const int c = (tid & 3) * 8;
        const int row = row0 + r;
        float v[8] = {0.f, 0.f, 0.f, 0.f, 0.f, 0.f, 0.f, 0.f};
        if (row < M) {
            *reinterpret_cast<float4*>(&v[0]) =
                *reinterpret_cast<const float4*>(&x[(size_t)row * 32 + c]);
            *reinterpret_cast<float4*>(&v[4]) =
                *reinterpret_cast<const float4*>(&x[(size_t)row * 32 + c + 4]);
        }
#pragma unroll
        for (int j = 0; j < 8; ++j) As[(c + j) * 64 + r] = v[j];
    }
    // stage W1 -> Ws (direct copy, [k][n])
    {
        const int e0 = tid * 8;
        *reinterpret_cast<float4*>(&Ws[e0]) =
            *reinterpret_cast<const float4*>(&W1[e0]);
        *reinterpret_cast<float4*>(&Ws[e0 + 4]) =
            *reinterpret_cast<const float4*>(&W1[e0 + 4]);
    }
    __syncthreads();

    // stage 1: h1 = relu(x@W1 + b1)
    float acc[4][4] = {{0.f}};
#pragma unroll
    for (int k = 0; k < 32; ++k) {
        float a[4], b[4];
        *reinterpret_cast<float4*>(a) =
            *reinterpret_cast<const float4*>(&As[k * 64 + ty * 4]);
        *reinterpret_cast<float4*>(b) =
            *reinterpret_cast<const float4*>(&Ws[k * 64 + tx * 4]);
#pragma unroll
        for (int i = 0; i < 4; ++i)
#pragma unroll
            for (int j = 0; j < 4; ++j)
                acc[i][j] = fmaf(a[i], b[j], acc[i][j]);
    }
#pragma unroll
    for (int j = 0; j < 4; ++j) {
        const float bj = b1[tx * 4 + j];
#pragma unroll
        for (int i = 0; i < 4; ++i)
            Hs[(tx * 4 + j) * 68 + ty * 4 + i] = fmaxf(acc[i][j] + bj, 0.f);
    }
    __syncthreads();                 // Hs done AND As/Ws reads done

    // stage W2 -> Ws2 (overwrites As/Ws)
    {
        const int e0 = tid * 16;
#pragma unroll
        for (int q = 0; q < 4; ++q)
            *reinterpret_cast<float4*>(&Ws2[e0 + q * 4]) =
                *reinterpret_cast<const float4*>(&W2[e0 + q * 4]);
    }
    __syncthreads();

    // stage 2: h2 = relu(h1@W2 + b2)
    float acc2[4][4] = {{0.f}};
#pragma unroll
    for (int k = 0; k < 64; ++k) {
        float a[4], b[4];
        *reinterpret_cast<float4*>(a) =
            *reinterpret_cast<const float4*>(&Hs[k * 68 + ty * 4]);
        *reinterpret_cast<float4*>(b) =
            *reinterpret_cast<const float4*>(&Ws2[k * 64 + tx * 4]);
#pragma unroll
        for (int i = 0; i < 4; ++i)
#pragma unroll
            for (int j = 0; j < 4; ++j)
                acc2[i][j] = fmaf(a[i], b[j], acc2[i][j]);
    }
    const int cbase = tx * 4;
    float bv[4];
    *reinterpret_cast<float4*>(bv) =
        *reinterpret_cast<const float4*>(&b2[cbase]);
#pragma unroll
    for (int i = 0; i < 4; ++i) {
        const int row = row0 + ty * 4 + i;
        if (row >= M) continue;
        short4 s;
        s.x = (short)f2bf(fmaxf(acc2[i][0] + bv[0], 0.f));
        s.y = (short)f2bf(fmaxf(acc2[i][1] + bv[1], 0.f));
        s.z = (short)f2bf(fmaxf(acc2[i][2] + bv[2], 0.f));
        s.w = (short)f2bf(fmaxf(acc2[i][3] + bv[3], 0.f));
        *reinterpret_cast<short4*>(&h2b[(size_t)row * 64 + cbase]) = s;
    }
}

// ---------- all 4 weight transposes + bf16 convert in one launch ----------
__global__ void wtrans_all_k(
    const float* __restrict__ Wl1, const float* __restrict__ Wr1,
    const float* __restrict__ Wl2, const float* __restrict__ Wr2,
    short* __restrict__ o1, short* __restrict__ o2,
    short* __restrict__ o3, short* __restrict__ o4)
{
    const int i = blockIdx.x * 256 + threadIdx.x;
    const int S1 = 256 * 64, S2 = 256 * 256;
    if (i < S1) {
        const int n = i / 64, k = i % 64;
        o1[i] = (short)f2bf(Wl1[(size_t)k * 256 + n]);
    } else if (i < 2 * S1) {
        const int j = i - S1;
        const int n = j / 64, k = j % 64;
        o2[j] = (short)f2bf(Wr1[(size_t)k * 256 + n]);
    } else if (i < 2 * S1 + S2) {
        const int j = i - 2 * S1;
        const int n = j / 256, k = j % 256;
        o3[j] = (short)f2bf(Wl2[(size_t)k * 256 + n]);
    } else if (i < 2 * S1 + 2 * S2) {
        const int j = i - 2 * S1 - S2;
        const int n = j / 256, k = j % 256;
        o4[j] = (short)f2bf(Wr2[(size_t)k * 256 + n]);
    }
}

// ---------- MFMA dual GEMM: {out0,out1} = bf16(A @ {W0,W1} + {b0,b1}) ----------
__global__ __launch_bounds__(256) void gemm_mfma_dual(
    const short* __restrict__ A,
    const short* __restrict__ Wt0, const float* __restrict__ b0,
    short* __restrict__ out0,
    const short* __restrict__ Wt1, const float* __restrict__ b1,
    short* __restrict__ out1,
    int M, int N, int K)
{
    const short* __restrict__ Wt   = blockIdx.z ? Wt1 : Wt0;
    const float* __restrict__ bias = blockIdx.z ? b1 : b0;
    short* __restrict__ out        = blockIdx.z ? out1 : out0;

    __shared__ __align__(16) short As[4][128][8];
    __shared__ __align__(16) short Bs[4][128][8];

    const int tid = threadIdx.x;
    const int lane = tid & 63;
    const int wid = tid >> 6;
    const int wm = wid >> 1, wn = wid & 1;
    const int row0 = blockIdx.x * 128;
    const int col0 = blockIdx.y * 128;

    f32x4 acc[4][4] = {};

    const int srow = tid & 127;
    const int skg2 = tid >> 7;

    for (int kk = 0; kk < K; kk += 32) {
        {
            const int r = row0 + srow;
            bf16x8 a0 = {0, 0, 0, 0, 0, 0, 0, 0};
            bf16x8 a1 = {0, 0, 0, 0, 0, 0, 0, 0};
            if (r < M) {
                const bf16x8* p = reinterpret_cast<const bf16x8*>(
                    &A[(size_t)r * K + kk + skg2 * 16]);
                a0 = p[0]; a1 = p[1];
            }
            *reinterpret_cast<bf16x8*>(&As[skg2 * 2 + 0][srow][0]) = a0;
            *reinterpret_cast<bf16x8*>(&As[skg2 * 2 + 1][srow][0]) = a1;
        }
        {
            const float4* p = reinterpret_cast<const float4*>(
                &Wt[(size_t)(col0 + srow) * K + kk + skg2 * 16]);
            *reinterpret_cast<float4*>(&Bs[skg2 * 2 + 0][srow][0]) = p[0];
            *reinterpret_cast<float4*>(&Bs[skg2 * 2 + 1][srow][0]) = p[1];
        }
        __syncthreads();

        const int kg = lane >> 4, li = lane & 15;
        bf16x8 af[4], bfr[4];
#pragma unroll
        for (int mi = 0; mi < 4; ++mi)
            af[mi] = *reinterpret_cast<bf16x8*>(&As[kg][wm * 64 + mi * 16 + li][0]);
#pragma unroll
        for (int ni = 0; ni < 4; ++ni)
            bfr[ni] = *reinterpret_cast<bf16x8*>(&Bs[kg][wn * 64 + ni * 16 + li][0]);
#pragma unroll
        for (int mi = 0; mi < 4; ++mi)
#pragma unroll
            for (int ni = 0; ni < 4; ++ni)
                acc[mi][ni] = __builtin_amdgcn_mfma_f32_16x16x32_bf16(
                    af[mi], bfr[ni], acc[mi][ni], 0, 0, 0);
        __syncthreads();
    }

    const int li = lane & 15, lq = lane >> 4;
#pragma unroll
    for (int ni = 0; ni < 4; ++ni) {
        const int c = col0 + wn * 64 + ni * 16 + li;
        const float bv = bias[c];
#pragma unroll
        for (int mi = 0; mi < 4; ++mi) {
#pragma unroll
            for (int r = 0; r < 4; ++r) {
                const int row = row0 + wm * 64 + mi * 16 + lq * 4 + r;
                if (row < M)
                    out[(size_t)row * N + c] = (short)f2bf(acc[mi][ni][r] + bv);
            }
        }
    }
}

// ---------- CSR build ----------
__global__ void hist_k(const int* __restrict__ dst, int* __restrict__ deg, int E)
{
    const int e = blockIdx.x * blockDim.x + threadIdx.x;
    if (e < E) atomicAdd(&deg[dst[e]], 1);
}

__global__ void scan1_k(const int* __restrict__ deg, int* __restrict__ rowptr,
                        int* __restrict__ bsum, int N)
{
    __shared__ int buf[256];
    const int i = blockIdx.x * 256 + threadIdx.x;
    const int v = (i < N) ? deg[i] : 0;
    buf[threadIdx.x] = v;
    __syncthreads();
#pragma unroll
    for (int off = 1; off < 256; off <<= 1) {
        const int t = (threadIdx.x >= (unsigned)off) ? buf[threadIdx.x - off] : 0;
        __syncthreads();
        buf[threadIdx.x] += t;
        __syncthreads();
    }
    if (i < N) rowptr[i] = buf[threadIdx.x] - v;
    if (threadIdx.x == 255) bsum[blockIdx.x] = buf[255];
}

__global__ void scan2_k(int* __restrict__ bsum, int nb)
{
    __shared__ int buf[256];
    const int v = (threadIdx.x < (unsigned)nb) ? bsum[threadIdx.x] : 0;
    buf[threadIdx.x] = v;
    __syncthreads();
#pragma unroll
    for (int off = 1; off < 256; off <<= 1) {
        const int t = (threadIdx.x >= (unsigned)off) ? buf[threadIdx.x - off] : 0;
        __syncthreads();
        buf[threadIdx.x] += t;
        __syncthreads();
    }
    if (threadIdx.x < (unsigned)nb) bsum[threadIdx.x] = buf[threadIdx.x] - v;
}

__global__ void scan3_k(int* __restrict__ rowptr, const int* __restrict__ bsum,
                        int* __restrict__ cursor, int N, int E)
{
    const int i = blockIdx.x * 256 + threadIdx.x;
    if (i < N) {
        const int r = rowptr[i] + bsum[blockIdx.x];
        rowptr[i] = r;
        cursor[i] = r;
    }
    if (i == 0) rowptr[N] = E;
}

// scatter src AND the eattr payload into dst-sorted order
__global__ void scatter_k(const int* __restrict__ src, const int* __restrict__ dst,
                          const float4* __restrict__ eattr,
                          int* __restrict__ cursor,
                          int* __restrict__ ssrc, float4* __restrict__ ea_s, int E)
{
    const int e = blockIdx.x * blockDim.x + threadIdx.x;
    if (e >= E) return;
    const int d = dst[e];
    const int p = atomicAdd(&cursor[d], 1);
    ssrc[p] = src[e];
    const float4 e0 = eattr[2 * e];
    const float4 e1 = eattr[2 * e + 1];
    ea_s[2 * p] = e0;
    ea_s[2 * p + 1] = e1;
}

// ---------- fused node-centric GATv2 (scalar-uniform edge loads + DPP reduce) ----------
// r13 config: ONE WAVE PER BLOCK, NPW=4, 52 VGPR, no spills — the measured
// optimum. ERRATA r11/r12/r15/r16: reg-pipelining, waves/EU=8, raw-uint2
// prefetch, and 2-wave blocks ALL regress — the kernel jointly saturates
// L2-miss gather bandwidth (~2 TB/s) and VALU issue (~62%).
template <int H, int NPW, int OB>
__global__ __launch_bounds__(64, 4) void node_gat_k(
    const short* __restrict__ xl, const short* __restrict__ xr,
    const float4* __restrict__ ea_s, const int* __restrict__ ssrc,
    const float* __restrict__ We, const float* __restrict__ att,
    const float* __restrict__ bias,
    const int* __restrict__ rowptr, void* __restrict__ outv, int N)
{
    const int lane = threadIdx.x;
    const int nbase = blockIdx.x * NPW;
    if (nbase >= N) return;

    const int hc0 = (H == 4) ? (((lane >> 4) << 6) + ((lane & 15) << 2))
                             : (lane << 2);

    f32x2 we2[8][2];
#pragma unroll
    for (int t = 0; t < 8; ++t) {
        const float4 v = *reinterpret_cast<const float4*>(&We[t * 256 + hc0]);
        we2[t][0] = (f32x2){v.x, v.y};
        we2[t][1] = (f32x2){v.z, v.w};
    }
    const float4 a4 = *reinterpret_cast<const float4*>(&att[hc0]);
    const f32x2 av2[2] = {(f32x2){a4.x, a4.y}, (f32x2){a4.z, a4.w}};
    const float4 b4 = *reinterpret_cast<const float4*>(&bias[hc0]);
    const f32x2 bv2[2] = {(f32x2){b4.x, b4.y}, (f32x2){b4.z, b4.w}};

    for (int ni = 0; ni < NPW; ++ni) {
        const int n = nbase + ni;
        if (n >= N) return;
        const uint2 rp = *reinterpret_cast<const uint2*>(
            &xr[(unsigned)((n << 8) + hc0)]);
        const f32x2 xrv2[2] = {bf2f2(rp.x), bf2f2(rp.y)};

        f32x2 acc2[2] = {(f32x2){0.f, 0.f}, (f32x2){0.f, 0.f}};
        float m = -INFINITY, den = 0.f;

        // wave-uniform loop bounds -> scalar loop, scalar edge loads
        const int k0 = __builtin_amdgcn_readfirstlane(rowptr[n]);
        const int k1 = __builtin_amdgcn_readfirstlane(rowptr[n + 1]);

        auto load_e = [&](const int ks, f32x2 (&xv)[2], float (&ea)[8]) {
            const int sv = ssrc[ks];                       // uniform -> s_load
            const short* xp = xl + ((unsigned)sv << 8);    // uniform base
            const uint2 xpv = *reinterpret_cast<const uint2*>(xp + hc0);
            xv[0] = bf2f2(xpv.x);
            xv[1] = bf2f2(xpv.y);
            const float4 e0 = ea_s[2 * ks];                // uniform -> s_load
            const float4 e1 = ea_s[2 * ks + 1];
            ea[0] = e0.x; ea[1] = e0.y; ea[2] = e0.z; ea[3] = e0.w;
            ea[4] = e1.x; ea[5] = e1.y; ea[6] = e1.z; ea[7] = e1.w;
        };
        auto sc_of = [&](const f32x2 (&xv)[2], const float (&ea)[8]) -> float {
            f32x2 p2 = {0.f, 0.f};
#pragma unroll
            for (int q = 0; q < 2; ++q) {
                f32x2 s = xv[q] + xrv2[q];
#pragma unroll
                for (int t = 0; t < 8; ++t)
                    s = pk_fma((f32x2){ea[t], ea[t]}, we2[t][q], s);
                s = pk_max(s, s * LR_SLOPE);       // packed leaky relu
                p2 = pk_fma(s, av2[q], p2);
            }
            float p = p2.x + p2.y;
            // 16-lane rotation reduce on the VALU (no LDS round-trips)
            p = add_dpp<0x121>(p);   // row_ror:1
            p = add_dpp<0x122>(p);   // row_ror:2
            p = add_dpp<0x124>(p);   // row_ror:4
            p = add_dpp<0x128>(p);   // row_ror:8
            if (H == 1) {
                p += __int_as_float(__builtin_amdgcn_ds_swizzle(
                         __float_as_int(p), 0x401F));      // xor 16
                p += __shfl_xor(p, 32, 64);                // xor 32
            }
            return p;
        };

        int k = k0;
        for (; k + 4 <= k1; k += 4) {
            f32x2 x0[2], x1[2], x2[2], x3[2];
            float ea0[8], ea1[8], ea2[8], ea3[8];
            load_e(k, x0, ea0);     load_e(k + 1, x1, ea1);
            load_e(k + 2, x2, ea2); load_e(k + 3, x3, ea3);
            const float s0 = sc_of(x0, ea0);
            const float s1 = sc_of(x1, ea1);
            const float s2 = sc_of(x2, ea2);
            const float s3 = sc_of(x3, ea3);
            const float nm = fmaxf(fmaxf(m, fmaxf(s0, s1)), fmaxf(s2, s3));
            const float sc = __expf(m - nm);
            const float w0 = __expf(s0 - nm), w1 = __expf(s1 - nm);
            const float w2 = __expf(s2 - nm), w3 = __expf(s3 - nm);
            den = fmaf(den, sc, (w0 + w1) + (w2 + w3));
            const f32x2 scv = {sc, sc};
            const f32x2 w0v = {w0, w0}, w1v = {w1, w1};
            const f32x2 w2v = {w2, w2}, w3v = {w3, w3};
#pragma unroll
            for (int q = 0; q < 2; ++q)
                acc2[q] = pk_fma(acc2[q], scv,
                          pk_fma(w0v, x0[q],
                          pk_fma(w1v, x1[q],
                          pk_fma(w2v, x2[q], w3v * x3[q]))));
            m = nm;
        }
        for (; k < k1; ++k) {
            f32x2 x0[2]; float ea0[8];
            load_e(k, x0, ea0);
            const float s0 = sc_of(x0, ea0);
            const float nm = fmaxf(m, s0);
            const float sc = __expf(m - nm);
            const float w0 = __expf(s0 - nm);
            den = fmaf(den, sc, w0);
            const f32x2 scv = {sc, sc};
            const f32x2 w0v = {w0, w0};
#pragma unroll
            for (int q = 0; q < 2; ++q)
                acc2[q] = pk_fma(acc2[q], scv, w0v * x0[q]);
            m = nm;
        }

        const float inv = (den > 0.f) ? 1.f / den : 0.f;
        const f32x2 invv = {inv, inv};
        const f32x2 z2 = {0.f, 0.f};
        const f32x2 o0 = pk_max(pk_fma(acc2[0], invv, bv2[0]), z2);
        const f32x2 o1 = pk_max(pk_fma(acc2[1], invv, bv2[1]), z2);
        if (OB) {
            short4 s;
            s.x = (short)f2bf(o0.x); s.y = (short)f2bf(o0.y);
            s.z = (short)f2bf(o1.x); s.w = (short)f2bf(o1.y);
            *reinterpret_cast<short4*>(
                &((short*)outv)[(unsigned)((n << 8) + hc0)]) = s;
        } else {
            float4 o; o.x = o0.x; o.y = o0.y; o.z = o1.x; o.w = o1.y;
            *reinterpret_cast<float4*>(
                &((float*)outv)[(unsigned)((n << 8) + hc0)]) = o;
        }
    }
}

extern "C" void kernel_launch(void* const* d_in, const int* in_sizes, int n_in,
                              void* d_out, int out_size, void* d_ws, size_t ws_size,
                              hipStream_t stream)
{
    const float* x     = (const float*)d_in[0];
    const int*   eidx  = (const int*)d_in[1];
    const float* eattr = (const float*)d_in[2];
    const float* W1  = (const float*)d_in[3];
    const float* b1  = (const float*)d_in[4];
    const float* W2  = (const float*)d_in[5];
    const float* b2  = (const float*)d_in[6];
    const float* Wl1 = (const float*)d_in[7];
    const float* bl1 = (const float*)d_in[8];
    const float* Wr1 = (const float*)d_in[9];
    const float* br1 = (const float*)d_in[10];
    const float* We1 = (const float*)d_in[11];
    const float* att1 = (const float*)d_in[12];
    const float* bias1 = (const float*)d_in[13];
    const float* Wl2 = (const float*)d_in[14];
    const float* bl2 = (const float*)d_in[15];
    const float* Wr2 = (const float*)d_in[16];
    const float* br2 = (const float*)d_in[17];
    const float* We2 = (const float*)d_in[18];
    const float* att2 = (const float*)d_in[19];
    const float* bias2 = (const float*)d_in[20];

    const int N = in_sizes[0] / 32;        // 50000
    const int E = in_sizes[2] / 8;         // 800000
    const int* src = eidx;
    const int* dst = eidx + E;

    // ---- workspace layout (r11-style: no h1, ea_s standalone) ----
    auto align256 = [](size_t v) { return (v + 255) & ~(size_t)255; };
    char* ws = (char*)d_ws;
    size_t off = 0;
    short* h2b = (short*)(ws + off);   off += align256((size_t)N * 64 * 2);
    float4* ea_s = (float4*)(ws + off); off += align256((size_t)E * 32);
    short* xl = (short*)(ws + off);    off += align256((size_t)N * 256 * 2);
    short* xr = (short*)(ws + off);    off += align256((size_t)N * 256 * 2);
    short* out1b = (short*)(ws + off); off += align256((size_t)N * 256 * 2);
    int* deg = (int*)(ws + off);       off += align256((size_t)N * 4);
    int* rowptr = (int*)(ws + off);    off += align256((size_t)(N + 1) * 4);
    int* cursor = (int*)(ws + off);    off += align256((size_t)N * 4);
    int* bsum = (int*)(ws + off);      off += align256((size_t)1024 * 4);
    int* ssrc = (int*)(ws + off);      off += align256((size_t)E * 4);
    short* wtl1 = (short*)(ws + off);  off += align256((size_t)256 * 64 * 2);
    short* wtr1 = (short*)(ws + off);  off += align256((size_t)256 * 64 * 2);
    short* wtl2 = (short*)(ws + off);  off += align256((size_t)256 * 256 * 2);
    short* wtr2 = (short*)(ws + off);  off += align256((size_t)256 * 256 * 2);
    (void)ws_size;

    float* outf = (float*)d_out;

    const int egrid1 = (E + 255) / 256;
    const int nblk = (N + 255) / 256;
    const int NPW = 4;
    const int ngat = (N + NPW - 1) / NPW;   // one wave (64 thr) per block

    // ---- weight transposes (bf16), one launch ----
    wtrans_all_k<<<(2 * 256 * 64 + 2 * 256 * 256 + 255) / 256, 256, 0, stream>>>(
        Wl1, Wr1, Wl2, Wr2, wtl1, wtr1, wtl2, wtr2);

    // ---- fused MLP encoder: x -> h2b (bf16), one kernel ----
    fused_mlp_k<<<(N + 63) / 64, 256, 0, stream>>>(x, W1, b1, W2, b2, h2b, N);

    // ---- GAT layer 1 transforms (bf16 MFMA): h2b -> xl, xr (bf16) ----
    {
        dim3 g((N + 127) / 128, 2, 2);
        gemm_mfma_dual<<<g, 256, 0, stream>>>(h2b, wtl1, bl1, xl, wtr1, br1, xr,
                                              N, 256, 64);
    }

    // ---- CSR build ----
    hipMemsetAsync(deg, 0, (size_t)N * 4, stream);
    hist_k<<<egrid1, 256, 0, stream>>>(dst, deg, E);
    scan1_k<<<nblk, 256, 0, stream>>>(deg, rowptr, bsum, N);
    scan2_k<<<1, 256, 0, stream>>>(bsum, nblk);
    scan3_k<<<nblk, 256, 0, stream>>>(rowptr, bsum, cursor, N, E);
    scatter_k<<<egrid1, 256, 0, stream>>>(src, dst, (const float4*)eattr,
                                          cursor, ssrc, ea_s, E);

    // ---- GAT layer 1 fused edge/softmax/agg (bf16 out) ----
    node_gat_k<4, NPW, 1><<<ngat, 64, 0, stream>>>(xl, xr, ea_s, ssrc,
                                                   We1, att1, bias1,
                                                   rowptr, out1b, N);

    // ---- GAT layer 2 transforms (bf16 MFMA): out1b -> xl, xr (bf16) ----
    {
        dim3 g((N + 127) / 128, 2, 2);
        gemm_mfma_dual<<<g, 256, 0, stream>>>(out1b, wtl2, bl2, xl, wtr2, br2, xr,
                                              N, 256, 256);
    }

    // ---- GAT layer 2 fused edge/softmax/agg (fp32 out) ----
    node_gat_k<1, NPW, 0><<<ngat, 64, 0, stream>>>(xl, xr, ea_s, ssrc,
                                                   We2, att2, bias2,
                                                   rowptr, outf, N);
}

// Round 18
// 401.540 us; speedup vs baseline: 1.0516x; 1.0407x over previous
//
#include <hip/hip_runtime.h>
#include <hip/hip_bf16.h>
#include <math.h>

#define LR_SLOPE 0.2f

typedef __attribute__((ext_vector_type(8))) short bf16x8;
typedef __attribute__((ext_vector_type(4))) float f32x4;
typedef __attribute__((ext_vector_type(2))) float f32x2;

// fp32 -> bf16 round-to-nearest-even (bit trick)
__device__ __forceinline__ unsigned short f2bf(float f) {
    unsigned u = __float_as_uint(f);
    u = (u + 0x7FFFu + ((u >> 16) & 1u)) >> 16;
    return (unsigned short)u;
}

// 2 packed bf16 (one u32) -> f32x2
__device__ __forceinline__ f32x2 bf2f2(unsigned u) {
    f32x2 r;
    r.x = __uint_as_float(u << 16);
    r.y = __uint_as_float(u & 0xffff0000u);
    return r;
}

// packed 2xfp32 helpers -> v_pk_fma_f32 / v_pk_max_f32 on CDNA
__device__ __forceinline__ f32x2 pk_fma(f32x2 a, f32x2 b, f32x2 c) {
    return __builtin_elementwise_fma(a, b, c);
}
__device__ __forceinline__ f32x2 pk_max(f32x2 a, f32x2 b) {
    return __builtin_elementwise_max(a, b);
}

// v_add_f32 with DPP row-rotate: p += rotate_within_16(p, CTRL). Pure VALU.
template <int CTRL>
__device__ __forceinline__ float add_dpp(float v) {
    const int r = __builtin_amdgcn_update_dpp(0, __float_as_int(v),
                                              CTRL, 0xF, 0xF, true);
    return v + __int_as_float(r);
}

// ---------- small GEMM (MLP, N=64): out = act(A@W + bias), fp32 or bf16 out ----------
// ERRATA r17: fusing the two MLP GEMMs into one kernel costs ~15us (3 syncs +
// 28.7KB LDS kill cross-CU overlap); two separate launches are faster.
__global__ __launch_bounds__(256) void gemm_bias_act(
    const float* __restrict__ A, const float* __restrict__ W,
    const float* __restrict__ bias, float* __restrict__ outf,
    short* __restrict__ outb, int M, int N, int K, int do_relu)
{
    __shared__ float As[16][64];
    __shared__ float Ws[16][64];
    const int tid = threadIdx.x;
    const int tx = tid & 15;
    const int ty = tid >> 4;
    const int row0 = blockIdx.x * 64;
    const int col0 = blockIdx.y * 64;

    float acc[4][4] = {{0.f}};

    for (int kk = 0; kk < K; kk += 16) {
        {
            const int ra = tid >> 2;
            const int ka = (tid & 3) << 2;
            float4 v = make_float4(0.f, 0.f, 0.f, 0.f);
            const int r = row0 + ra;
            if (r < M)
                v = *reinterpret_cast<const float4*>(&A[(size_t)r * K + kk + ka]);
            As[ka + 0][ra] = v.x;
            As[ka + 1][ra] = v.y;
            As[ka + 2][ra] = v.z;
            As[ka + 3][ra] = v.w;
        }
        {
            const int rw = tid >> 4;
            const int cw = (tid & 15) << 2;
            float4 v = *reinterpret_cast<const float4*>(
                &W[(size_t)(kk + rw) * N + col0 + cw]);
            *reinterpret_cast<float4*>(&Ws[rw][cw]) = v;
        }
        __syncthreads();
#pragma unroll
        for (int k = 0; k < 16; ++k) {
            const float4 a = *reinterpret_cast<const float4*>(&As[k][ty * 4]);
            const float4 b = *reinterpret_cast<const float4*>(&Ws[k][tx * 4]);
            const float av[4] = {a.x, a.y, a.z, a.w};
            const float bv[4] = {b.x, b.y, b.z, b.w};
#pragma unroll
            for (int i = 0; i < 4; ++i)
#pragma unroll
                for (int j = 0; j < 4; ++j)
                    acc[i][j] += av[i] * bv[j];
        }
        __syncthreads();
    }

    const int cbase = col0 + tx * 4;
#pragma unroll
    for (int i = 0; i < 4; ++i) {
        const int r = row0 + ty * 4 + i;
        if (r >= M) continue;
        float v[4];
#pragma unroll
        for (int j = 0; j < 4; ++j) {
            v[j] = acc[i][j] + bias[cbase + j];
            if (do_relu) v[j] = fmaxf(v[j], 0.f);
        }
        if (outb) {
            short4 s;
            s.x = (short)f2bf(v[0]); s.y = (short)f2bf(v[1]);
            s.z = (short)f2bf(v[2]); s.w = (short)f2bf(v[3]);
            *reinterpret_cast<short4*>(&outb[(size_t)r * N + cbase]) = s;
        } else {
            float4 o; o.x = v[0]; o.y = v[1]; o.z = v[2]; o.w = v[3];
            *reinterpret_cast<float4*>(&outf[(size_t)r * N + cbase]) = o;
        }
    }
}

// ---------- all 4 weight transposes + bf16 convert in one launch ----------
__global__ void wtrans_all_k(
    const float* __restrict__ Wl1, const float* __restrict__ Wr1,
    const float* __restrict__ Wl2, const float* __restrict__ Wr2,
    short* __restrict__ o1, short* __restrict__ o2,
    short* __restrict__ o3, short* __restrict__ o4)
{
    const int i = blockIdx.x * 256 + threadIdx.x;
    const int S1 = 256 * 64, S2 = 256 * 256;
    if (i < S1) {
        const int n = i / 64, k = i % 64;
        o1[i] = (short)f2bf(Wl1[(size_t)k * 256 + n]);
    } else if (i < 2 * S1) {
        const int j = i - S1;
        const int n = j / 64, k = j % 64;
        o2[j] = (short)f2bf(Wr1[(size_t)k * 256 + n]);
    } else if (i < 2 * S1 + S2) {
        const int j = i - 2 * S1;
        const int n = j / 256, k = j % 256;
        o3[j] = (short)f2bf(Wl2[(size_t)k * 256 + n]);
    } else if (i < 2 * S1 + 2 * S2) {
        const int j = i - 2 * S1 - S2;
        const int n = j / 256, k = j % 256;
        o4[j] = (short)f2bf(Wr2[(size_t)k * 256 + n]);
    }
}

// ---------- MFMA dual GEMM: {out0,out1} = bf16(A @ {W0,W1} + {b0,b1}) ----------
__global__ __launch_bounds__(256) void gemm_mfma_dual(
    const short* __restrict__ A,
    const short* __restrict__ Wt0, const float* __restrict__ b0,
    short* __restrict__ out0,
    const short* __restrict__ Wt1, const float* __restrict__ b1,
    short* __restrict__ out1,
    int M, int N, int K)
{
    const short* __restrict__ Wt   = blockIdx.z ? Wt1 : Wt0;
    const float* __restrict__ bias = blockIdx.z ? b1 : b0;
    short* __restrict__ out        = blockIdx.z ? out1 : out0;

    __shared__ __align__(16) short As[4][128][8];
    __shared__ __align__(16) short Bs[4][128][8];

    const int tid = threadIdx.x;
    const int lane = tid & 63;
    const int wid = tid >> 6;
    const int wm = wid >> 1, wn = wid & 1;
    const int row0 = blockIdx.x * 128;
    const int col0 = blockIdx.y * 128;

    f32x4 acc[4][4] = {};

    const int srow = tid & 127;
    const int skg2 = tid >> 7;

    for (int kk = 0; kk < K; kk += 32) {
        {
            const int r = row0 + srow;
            bf16x8 a0 = {0, 0, 0, 0, 0, 0, 0, 0};
            bf16x8 a1 = {0, 0, 0, 0, 0, 0, 0, 0};
            if (r < M) {
                const bf16x8* p = reinterpret_cast<const bf16x8*>(
                    &A[(size_t)r * K + kk + skg2 * 16]);
                a0 = p[0]; a1 = p[1];
            }
            *reinterpret_cast<bf16x8*>(&As[skg2 * 2 + 0][srow][0]) = a0;
            *reinterpret_cast<bf16x8*>(&As[skg2 * 2 + 1][srow][0]) = a1;
        }
        {
            const float4* p = reinterpret_cast<const float4*>(
                &Wt[(size_t)(col0 + srow) * K + kk + skg2 * 16]);
            *reinterpret_cast<float4*>(&Bs[skg2 * 2 + 0][srow][0]) = p[0];
            *reinterpret_cast<float4*>(&Bs[skg2 * 2 + 1][srow][0]) = p[1];
        }
        __syncthreads();

        const int kg = lane >> 4, li = lane & 15;
        bf16x8 af[4], bfr[4];
#pragma unroll
        for (int mi = 0; mi < 4; ++mi)
            af[mi] = *reinterpret_cast<bf16x8*>(&As[kg][wm * 64 + mi * 16 + li][0]);
#pragma unroll
        for (int ni = 0; ni < 4; ++ni)
            bfr[ni] = *reinterpret_cast<bf16x8*>(&Bs[kg][wn * 64 + ni * 16 + li][0]);
#pragma unroll
        for (int mi = 0; mi < 4; ++mi)
#pragma unroll
            for (int ni = 0; ni < 4; ++ni)
                acc[mi][ni] = __builtin_amdgcn_mfma_f32_16x16x32_bf16(
                    af[mi], bfr[ni], acc[mi][ni], 0, 0, 0);
        __syncthreads();
    }

    const int li = lane & 15, lq = lane >> 4;
#pragma unroll
    for (int ni = 0; ni < 4; ++ni) {
        const int c = col0 + wn * 64 + ni * 16 + li;
        const float bv = bias[c];
#pragma unroll
        for (int mi = 0; mi < 4; ++mi) {
#pragma unroll
            for (int r = 0; r < 4; ++r) {
                const int row = row0 + wm * 64 + mi * 16 + lq * 4 + r;
                if (row < M)
                    out[(size_t)row * N + c] = (short)f2bf(acc[mi][ni][r] + bv);
            }
        }
    }
}

// ---------- CSR build ----------
__global__ void hist_k(const int* __restrict__ dst, int* __restrict__ deg, int E)
{
    const int e = blockIdx.x * blockDim.x + threadIdx.x;
    if (e < E) atomicAdd(&deg[dst[e]], 1);
}

__global__ void scan1_k(const int* __restrict__ deg, int* __restrict__ rowptr,
                        int* __restrict__ bsum, int N)
{
    __shared__ int buf[256];
    const int i = blockIdx.x * 256 + threadIdx.x;
    const int v = (i < N) ? deg[i] : 0;
    buf[threadIdx.x] = v;
    __syncthreads();
#pragma unroll
    for (int off = 1; off < 256; off <<= 1) {
        const int t = (threadIdx.x >= (unsigned)off) ? buf[threadIdx.x - off] : 0;
        __syncthreads();
        buf[threadIdx.x] += t;
        __syncthreads();
    }
    if (i < N) rowptr[i] = buf[threadIdx.x] - v;
    if (threadIdx.x == 255) bsum[blockIdx.x] = buf[255];
}

__global__ void scan2_k(int* __restrict__ bsum, int nb)
{
    __shared__ int buf[256];
    const int v = (threadIdx.x < (unsigned)nb) ? bsum[threadIdx.x] : 0;
    buf[threadIdx.x] = v;
    __syncthreads();
#pragma unroll
    for (int off = 1; off < 256; off <<= 1) {
        const int t = (threadIdx.x >= (unsigned)off) ? buf[threadIdx.x - off] : 0;
        __syncthreads();
        buf[threadIdx.x] += t;
        __syncthreads();
    }
    if (threadIdx.x < (unsigned)nb) bsum[threadIdx.x] = buf[threadIdx.x] - v;
}

__global__ void scan3_k(int* __restrict__ rowptr, const int* __restrict__ bsum,
                        int* __restrict__ cursor, int N, int E)
{
    const int i = blockIdx.x * 256 + threadIdx.x;
    if (i < N) {
        const int r = rowptr[i] + bsum[blockIdx.x];
        rowptr[i] = r;
        cursor[i] = r;
    }
    if (i == 0) rowptr[N] = E;
}

// scatter src AND the eattr payload into dst-sorted order
__global__ void scatter_k(const int* __restrict__ src, const int* __restrict__ dst,
                          const float4* __restrict__ eattr,
                          int* __restrict__ cursor,
                          int* __restrict__ ssrc, float4* __restrict__ ea_s, int E)
{
    const int e = blockIdx.x * blockDim.x + threadIdx.x;
    if (e >= E) return;
    const int d = dst[e];
    const int p = atomicAdd(&cursor[d], 1);
    ssrc[p] = src[e];
    const float4 e0 = eattr[2 * e];
    const float4 e1 = eattr[2 * e + 1];
    ea_s[2 * p] = e0;
    ea_s[2 * p + 1] = e1;
}

// ---------- fused node-centric GATv2 (scalar-uniform edge loads + DPP reduce) ----------
// r13 config: ONE WAVE PER BLOCK, NPW=4, 52 VGPR, no spills — the measured
// optimum (403us total). ERRATA r11/r12/r15/r16/r17: reg-pipelining, waves/EU=8,
// raw-uint2 prefetch, 2-wave blocks, fused-MLP ALL regress — the kernel jointly
// saturates L2-miss gather bandwidth (~2 TB/s random 512B) and VALU issue (~63%).
template <int H, int NPW, int OB>
__global__ __launch_bounds__(64, 4) void node_gat_k(
    const short* __restrict__ xl, const short* __restrict__ xr,
    const float4* __restrict__ ea_s, const int* __restrict__ ssrc,
    const float* __restrict__ We, const float* __restrict__ att,
    const float* __restrict__ bias,
    const int* __restrict__ rowptr, void* __restrict__ outv, int N)
{
    const int lane = threadIdx.x;
    const int nbase = blockIdx.x * NPW;
    if (nbase >= N) return;

    const int hc0 = (H == 4) ? (((lane >> 4) << 6) + ((lane & 15) << 2))
                             : (lane << 2);

    f32x2 we2[8][2];
#pragma unroll
    for (int t = 0; t < 8; ++t) {
        const float4 v = *reinterpret_cast<const float4*>(&We[t * 256 + hc0]);
        we2[t][0] = (f32x2){v.x, v.y};
        we2[t][1] = (f32x2){v.z, v.w};
    }
    const float4 a4 = *reinterpret_cast<const float4*>(&att[hc0]);
    const f32x2 av2[2] = {(f32x2){a4.x, a4.y}, (f32x2){a4.z, a4.w}};
    const float4 b4 = *reinterpret_cast<const float4*>(&bias[hc0]);
    const f32x2 bv2[2] = {(f32x2){b4.x, b4.y}, (f32x2){b4.z, b4.w}};

    for (int ni = 0; ni < NPW; ++ni) {
        const int n = nbase + ni;
        if (n >= N) return;
        const uint2 rp = *reinterpret_cast<const uint2*>(
            &xr[(unsigned)((n << 8) + hc0)]);
        const f32x2 xrv2[2] = {bf2f2(rp.x), bf2f2(rp.y)};

        f32x2 acc2[2] = {(f32x2){0.f, 0.f}, (f32x2){0.f, 0.f}};
        float m = -INFINITY, den = 0.f;

        // wave-uniform loop bounds -> scalar loop, scalar edge loads
        const int k0 = __builtin_amdgcn_readfirstlane(rowptr[n]);
        const int k1 = __builtin_amdgcn_readfirstlane(rowptr[n + 1]);

        auto load_e = [&](const int ks, f32x2 (&xv)[2], float (&ea)[8]) {
            const int sv = ssrc[ks];                       // uniform -> s_load
            const short* xp = xl + ((unsigned)sv << 8);    // uniform base
            const uint2 xpv = *reinterpret_cast<const uint2*>(xp + hc0);
            xv[0] = bf2f2(xpv.x);
            xv[1] = bf2f2(xpv.y);
            const float4 e0 = ea_s[2 * ks];                // uniform -> s_load
            const float4 e1 = ea_s[2 * ks + 1];
            ea[0] = e0.x; ea[1] = e0.y; ea[2] = e0.z; ea[3] = e0.w;
            ea[4] = e1.x; ea[5] = e1.y; ea[6] = e1.z; ea[7] = e1.w;
        };
        auto sc_of = [&](const f32x2 (&xv)[2], const float (&ea)[8]) -> float {
            f32x2 p2 = {0.f, 0.f};
#pragma unroll
            for (int q = 0; q < 2; ++q) {
                f32x2 s = xv[q] + xrv2[q];
#pragma unroll
                for (int t = 0; t < 8; ++t)
                    s = pk_fma((f32x2){ea[t], ea[t]}, we2[t][q], s);
                s = pk_max(s, s * LR_SLOPE);       // packed leaky relu
                p2 = pk_fma(s, av2[q], p2);
            }
            float p = p2.x + p2.y;
            // 16-lane rotation reduce on the VALU (no LDS round-trips)
            p = add_dpp<0x121>(p);   // row_ror:1
            p = add_dpp<0x122>(p);   // row_ror:2
            p = add_dpp<0x124>(p);   // row_ror:4
            p = add_dpp<0x128>(p);   // row_ror:8
            if (H == 1) {
                p += __int_as_float(__builtin_amdgcn_ds_swizzle(
                         __float_as_int(p), 0x401F));      // xor 16
                p += __shfl_xor(p, 32, 64);                // xor 32
            }
            return p;
        };

        int k = k0;
        for (; k + 4 <= k1; k += 4) {
            f32x2 x0[2], x1[2], x2[2], x3[2];
            float ea0[8], ea1[8], ea2[8], ea3[8];
            load_e(k, x0, ea0);     load_e(k + 1, x1, ea1);
            load_e(k + 2, x2, ea2); load_e(k + 3, x3, ea3);
            const float s0 = sc_of(x0, ea0);
            const float s1 = sc_of(x1, ea1);
            const float s2 = sc_of(x2, ea2);
            const float s3 = sc_of(x3, ea3);
            const float nm = fmaxf(fmaxf(m, fmaxf(s0, s1)), fmaxf(s2, s3));
            const float sc = __expf(m - nm);
            const float w0 = __expf(s0 - nm), w1 = __expf(s1 - nm);
            const float w2 = __expf(s2 - nm), w3 = __expf(s3 - nm);
            den = fmaf(den, sc, (w0 + w1) + (w2 + w3));
            const f32x2 scv = {sc, sc};
            const f32x2 w0v = {w0, w0}, w1v = {w1, w1};
            const f32x2 w2v = {w2, w2}, w3v = {w3, w3};
#pragma unroll
            for (int q = 0; q < 2; ++q)
                acc2[q] = pk_fma(acc2[q], scv,
                          pk_fma(w0v, x0[q],
                          pk_fma(w1v, x1[q],
                          pk_fma(w2v, x2[q], w3v * x3[q]))));
            m = nm;
        }
        for (; k < k1; ++k) {
            f32x2 x0[2]; float ea0[8];
            load_e(k, x0, ea0);
            const float s0 = sc_of(x0, ea0);
            const float nm = fmaxf(m, s0);
            const float sc = __expf(m - nm);
            const float w0 = __expf(s0 - nm);
            den = fmaf(den, sc, w0);
            const f32x2 scv = {sc, sc};
            const f32x2 w0v = {w0, w0};
#pragma unroll
            for (int q = 0; q < 2; ++q)
                acc2[q] = pk_fma(acc2[q], scv, w0v * x0[q]);
            m = nm;
        }

        const float inv = (den > 0.f) ? 1.f / den : 0.f;
        const f32x2 invv = {inv, inv};
        const f32x2 z2 = {0.f, 0.f};
        const f32x2 o0 = pk_max(pk_fma(acc2[0], invv, bv2[0]), z2);
        const f32x2 o1 = pk_max(pk_fma(acc2[1], invv, bv2[1]), z2);
        if (OB) {
            short4 s;
            s.x = (short)f2bf(o0.x); s.y = (short)f2bf(o0.y);
            s.z = (short)f2bf(o1.x); s.w = (short)f2bf(o1.y);
            *reinterpret_cast<short4*>(
                &((short*)outv)[(unsigned)((n << 8) + hc0)]) = s;
        } else {
            float4 o; o.x = o0.x; o.y = o0.y; o.z = o1.x; o.w = o1.y;
            *reinterpret_cast<float4*>(
                &((float*)outv)[(unsigned)((n << 8) + hc0)]) = o;
        }
    }
}

extern "C" void kernel_launch(void* const* d_in, const int* in_sizes, int n_in,
                              void* d_out, int out_size, void* d_ws, size_t ws_size,
                              hipStream_t stream)
{
    const float* x     = (const float*)d_in[0];
    const int*   eidx  = (const int*)d_in[1];
    const float* eattr = (const float*)d_in[2];
    const float* W1  = (const float*)d_in[3];
    const float* b1  = (const float*)d_in[4];
    const float* W2  = (const float*)d_in[5];
    const float* b2  = (const float*)d_in[6];
    const float* Wl1 = (const float*)d_in[7];
    const float* bl1 = (const float*)d_in[8];
    const float* Wr1 = (const float*)d_in[9];
    const float* br1 = (const float*)d_in[10];
    const float* We1 = (const float*)d_in[11];
    const float* att1 = (const float*)d_in[12];
    const float* bias1 = (const float*)d_in[13];
    const float* Wl2 = (const float*)d_in[14];
    const float* bl2 = (const float*)d_in[15];
    const float* Wr2 = (const float*)d_in[16];
    const float* br2 = (const float*)d_in[17];
    const float* We2 = (const float*)d_in[18];
    const float* att2 = (const float*)d_in[19];
    const float* bias2 = (const float*)d_in[20];

    const int N = in_sizes[0] / 32;        // 50000
    const int E = in_sizes[2] / 8;         // 800000
    const int* src = eidx;
    const int* dst = eidx + E;

    // ---- workspace layout (ea_s aliases h1+h2: both dead before CSR build) ----
    auto align256 = [](size_t v) { return (v + 255) & ~(size_t)255; };
    char* ws = (char*)d_ws;
    size_t off = 0;
    float* h1 = (float*)(ws + off);    off += align256((size_t)N * 64 * 4);
    short* h2b = (short*)(ws + off);   off += align256((size_t)N * 64 * 4);
    float4* ea_s = (float4*)h1;        // E*32B == N*128*4B exactly (25.6 MB)
    short* xl = (short*)(ws + off);    off += align256((size_t)N * 256 * 2);
    short* xr = (short*)(ws + off);    off += align256((size_t)N * 256 * 2);
    short* out1b = (short*)(ws + off); off += align256((size_t)N * 256 * 2);
    int* deg = (int*)(ws + off);       off += align256((size_t)N * 4);
    int* rowptr = (int*)(ws + off);    off += align256((size_t)(N + 1) * 4);
    int* cursor = (int*)(ws + off);    off += align256((size_t)N * 4);
    int* bsum = (int*)(ws + off);      off += align256((size_t)1024 * 4);
    int* ssrc = (int*)(ws + off);      off += align256((size_t)E * 4);
    short* wtl1 = (short*)(ws + off);  off += align256((size_t)256 * 64 * 2);
    short* wtr1 = (short*)(ws + off);  off += align256((size_t)256 * 64 * 2);
    short* wtl2 = (short*)(ws + off);  off += align256((size_t)256 * 256 * 2);
    short* wtr2 = (short*)(ws + off);  off += align256((size_t)256 * 256 * 2);
    (void)ws_size;

    float* outf = (float*)d_out;

    const int egrid1 = (E + 255) / 256;
    const int nblk = (N + 255) / 256;
    const int NPW = 4;
    const int ngat = (N + NPW - 1) / NPW;   // one wave (64 thr) per block

    // ---- weight transposes (bf16), one launch ----
    wtrans_all_k<<<(2 * 256 * 64 + 2 * 256 * 256 + 255) / 256, 256, 0, stream>>>(
        Wl1, Wr1, Wl2, Wr2, wtl1, wtr1, wtl2, wtr2);

    // ---- MLP encoder (h2 written as bf16 for the MFMA consumer) ----
    {
        dim3 g1((N + 63) / 64, 1);
        gemm_bias_act<<<g1, 256, 0, stream>>>(x,  W1, b1, h1, nullptr, N, 64, 32, 1);
        gemm_bias_act<<<g1, 256, 0, stream>>>(h1, W2, b2, nullptr, h2b, N, 64, 64, 1);
    }

    // ---- GAT layer 1 transforms (bf16 MFMA): h2b -> xl, xr (bf16) ----
    {
        dim3 g((N + 127) / 128, 2, 2);
        gemm_mfma_dual<<<g, 256, 0, stream>>>(h2b, wtl1, bl1, xl, wtr1, br1, xr,
                                              N, 256, 64);
    }

    // ---- CSR build (h1/h2 now dead; ea_s reuses their space) ----
    hipMemsetAsync(deg, 0, (size_t)N * 4, stream);
    hist_k<<<egrid1, 256, 0, stream>>>(dst, deg, E);
    scan1_k<<<nblk, 256, 0, stream>>>(deg, rowptr, bsum, N);
    scan2_k<<<1, 256, 0, stream>>>(bsum, nblk);
    scan3_k<<<nblk, 256, 0, stream>>>(rowptr, bsum, cursor, N, E);
    scatter_k<<<egrid1, 256, 0, stream>>>(src, dst, (const float4*)eattr,
                                          cursor, ssrc, ea_s, E);

    // ---- GAT layer 1 fused edge/softmax/agg (bf16 out) ----
    node_gat_k<4, NPW, 1><<<ngat, 64, 0, stream>>>(xl, xr, ea_s, ssrc,
                                                   We1, att1, bias1,
                                                   rowptr, out1b, N);

    // ---- GAT layer 2 transforms (bf16 MFMA): out1b -> xl, xr (bf16) ----
    {
        dim3 g((N + 127) / 128, 2, 2);
        gemm_mfma_dual<<<g, 256, 0, stream>>>(out1b, wtl2, bl2, xl, wtr2, br2, xr,
                                              N, 256, 256);
    }

    // ---- GAT layer 2 fused edge/softmax/agg (fp32 out) ----
    node_gat_k<1, NPW, 0><<<ngat, 64, 0, stream>>>(xl, xr, ea_s, ssrc,
                                                   We2, att2, bias2,
                                                   rowptr, outf, N);
}